// Round 7
// baseline (604.899 us; speedup 1.0000x reference)
//
#include <hip/hip_runtime.h>
#include <cstdint>

typedef _Float16 half8 __attribute__((ext_vector_type(8)));
typedef float f32x4 __attribute__((ext_vector_type(4)));

__device__ __forceinline__ void gload16(const void* g, void* l) {
  __builtin_amdgcn_global_load_lds(
      (const __attribute__((address_space(1))) void*)g,
      (__attribute__((address_space(3))) void*)l, 16, 0, 0);
}

// ---------------- kNN: one WAVE per query point, barrier-free selection ----------------
__global__ __launch_bounds__(256) void knn_kernel(const float* __restrict__ pos,
                                                  int* __restrict__ nbr) {
  __shared__ float px[1024], py[1024], pz[1024], sq[1024];
  int tid = threadIdx.x;
  int b = blockIdx.x >> 8;                 // graph id (256 blocks per graph)
  const float* pg = pos + (size_t)b * 3072;
  for (int m = 0; m < 4; ++m) {
    int j = m * 256 + tid;
    float x = pg[3 * j], y = pg[3 * j + 1], z = pg[3 * j + 2];
    px[j] = x; py[j] = y; pz[j] = z; sq[j] = x * x + y * y + z * z;
  }
  __syncthreads();
  int wave = tid >> 6, lane = tid & 63;
  int n = (blockIdx.x & 255) * 4 + wave;   // local query index in graph
  float xi = px[n], yi = py[n], zi = pz[n], si = sq[n];
  float d[16];
#pragma unroll
  for (int i = 0; i < 16; ++i) {
    int j = i * 64 + lane;
    float dd = si + sq[j] - 2.0f * (xi * px[j] + yi * py[j] + zi * pz[j]);
    d[i] = (j == n) ? 1e30f : dd;          // exclude self
  }
  int outbase = (b * 1024 + n) * 20;
  for (int kk = 0; kk < 20; ++kk) {
    float lmin = d[0]; int lpos = 0;
#pragma unroll
    for (int i = 1; i < 16; ++i)
      if (d[i] < lmin) { lmin = d[i]; lpos = i; }
    float bv = lmin; int bi = lpos * 64 + lane;
#pragma unroll
    for (int off = 1; off < 64; off <<= 1) {
      float ov = __shfl_xor(bv, off);
      int   oi = __shfl_xor(bi, off);
      if (ov < bv || (ov == bv && oi < bi)) { bv = ov; bi = oi; }
    }
    if (lane == 0) nbr[outbase + kk] = b * 1024 + bi;
    if ((bi & 63) == lane) {
      int rp = bi >> 6;
#pragma unroll
      for (int i = 0; i < 16; ++i)
        if (i == rp) d[i] = 1e30f;
    }
  }
}

// ---------------- edge MLP layer1 stats (sum, sumsq per channel) ----------------
__global__ __launch_bounds__(256) void edge_stats_kernel(
    const float* __restrict__ pos, const int* __restrict__ nbr,
    const float* __restrict__ W1, const float* __restrict__ b1v,
    float* __restrict__ psum, float* __restrict__ psq) {
  __shared__ float els[256][6];
  __shared__ float w1s[384];
  __shared__ float b1s[64];
  __shared__ float red[8][64];
  int tid = threadIdx.x, bid = blockIdx.x;
  for (int f = tid; f < 384; f += 256) w1s[f] = W1[f];
  if (tid < 64) b1s[tid] = b1v[tid];
  int c = tid & 63, grp = tid >> 6;
  float s = 0.f, s2 = 0.f;
  for (int ch = 0; ch < 5; ++ch) {
    int E = bid * 1280 + ch * 256 + tid;
    int p = E / 20;
    int j = nbr[E];
    float pix = pos[3 * p], piy = pos[3 * p + 1], piz = pos[3 * p + 2];
    float e3 = pos[3 * j] - pix, e4 = pos[3 * j + 1] - piy, e5 = pos[3 * j + 2] - piz;
    __syncthreads();
    els[tid][0] = pix; els[tid][1] = piy; els[tid][2] = piz;
    els[tid][3] = e3;  els[tid][4] = e4;  els[tid][5] = e5;
    __syncthreads();
    for (int m = 0; m < 64; ++m) {
      int e = grp * 64 + m;
      float h = b1s[c];
#pragma unroll
      for (int d = 0; d < 6; ++d) h += els[e][d] * w1s[d * 64 + c];
      s += h; s2 += h * h;
    }
  }
  red[grp][c] = s;
  __syncthreads();
  red[4 + grp][c] = s2;
  __syncthreads();
  if (tid < 64) {
    float S = red[0][tid] + red[1][tid] + red[2][tid] + red[3][tid];
    float Q = red[4][tid] + red[5][tid] + red[6][tid] + red[7][tid];
    psum[bid * 64 + tid] = S;
    psq[bid * 64 + tid] = Q;
  }
}

__global__ void bn_finalize_kernel(const float* __restrict__ psum, const float* __restrict__ psq,
                                   const float* __restrict__ gamma, const float* __restrict__ beta,
                                   float* __restrict__ bns, float* __restrict__ bnh) {
  int c = threadIdx.x;   // 64 threads
  float s = 0.f, q = 0.f;
  for (int b = 0; b < 512; ++b) { s += psum[b * 64 + c]; q += psq[b * 64 + c]; }
  const float inv = 1.0f / 655360.0f;
  float mu = s * inv;
  float var = q * inv - mu * mu;
  float sc = gamma[c] * rsqrtf(var + 1e-5f);
  bns[c] = sc;
  bnh[c] = beta[c] - mu * sc;
}

// ---------------- edge MLP via split-f16 MFMA (fp32-accurate) ----------------
__global__ __launch_bounds__(256) void edge_mlp_kernel(
    const float* __restrict__ pos, const int* __restrict__ nbr,
    const float* __restrict__ W1, const float* __restrict__ b1v,
    const float* __restrict__ bns, const float* __restrict__ bnh,
    const float* __restrict__ W2, const float* __restrict__ b2v,
    float* __restrict__ x1) {
  __shared__ __align__(16) char elds[53248];
  _Float16* Ah = (_Float16*)(elds);            // [80][64] swizzled, 10240 B
  _Float16* Al = (_Float16*)(elds + 10240);    // 10240 B
  _Float16* Bh = (_Float16*)(elds + 20480);    // [128 cols][64] swizzled, 16384 B
  _Float16* Bl = (_Float16*)(elds + 36864);    // 16384 B
  float* outb = (float*)elds;                  // [80][129] fp32, reused after MFMA
  __shared__ float w1s[384];
  __shared__ float b1s[64], scs[64], shs[64];
  int tid = threadIdx.x, bid = blockIdx.x;
  for (int f = tid; f < 384; f += 256) w1s[f] = W1[f];
  if (tid < 64) { b1s[tid] = b1v[tid]; scs[tid] = bns[tid]; shs[tid] = bnh[tid]; }
#pragma unroll
  for (int i = 0; i < 32; ++i) {
    int flat = tid + 256 * i;        // d = flat>>7 (0..63), c = flat&127
    int dd = flat >> 7, c = flat & 127;
    float v = W2[flat];
    _Float16 hi = (_Float16)v;
    _Float16 lo = (_Float16)(v - (float)hi);
    int byte = c * 128 + ((((dd >> 3) ^ (c & 7))) << 4) + (dd & 7) * 2;
    *(_Float16*)((char*)Bh + byte) = hi;
    *(_Float16*)((char*)Bl + byte) = lo;
  }
  __syncthreads();
#pragma unroll
  for (int m = 0; m < 20; ++m) {
    int flat = tid + 256 * m;
    int row = flat >> 6;            // 0..79
    int d = flat & 63;
    int j = nbr[bid * 80 + row];
    int P = bid * 4 + (row / 20);
    float pix = pos[3 * P], piy = pos[3 * P + 1], piz = pos[3 * P + 2];
    float e3 = pos[3 * j] - pix, e4 = pos[3 * j + 1] - piy, e5 = pos[3 * j + 2] - piz;
    float h = b1s[d];
    h += pix * w1s[d] + piy * w1s[64 + d] + piz * w1s[128 + d]
       + e3 * w1s[192 + d] + e4 * w1s[256 + d] + e5 * w1s[320 + d];
    h = scs[d] * h + shs[d];
    h = fmaxf(h, 0.f);
    _Float16 hi = (_Float16)h;
    _Float16 lo = (_Float16)(h - (float)hi);
    int byte = row * 128 + ((((d >> 3) ^ (row & 7))) << 4) + (d & 7) * 2;
    *(_Float16*)((char*)Ah + byte) = hi;
    *(_Float16*)((char*)Al + byte) = lo;
  }
  __syncthreads();
  int wave = tid >> 6, lane = tid & 63;
  int l15 = lane & 15, l4 = lane >> 4;
  f32x4 acc[5][2] = {};
#pragma unroll
  for (int ks = 0; ks < 2; ++ks) {
    int slotk = ks * 4 + l4;
    half8 bfh[2], bfl[2];
#pragma unroll
    for (int ci = 0; ci < 2; ++ci) {
      int col = (wave * 2 + ci) * 16 + l15;
      int byte = col * 128 + ((slotk ^ (col & 7)) << 4);
      bfh[ci] = *(const half8*)((char*)Bh + byte);
      bfl[ci] = *(const half8*)((char*)Bl + byte);
    }
#pragma unroll
    for (int rt = 0; rt < 5; ++rt) {
      int row = rt * 16 + l15;
      int byte = row * 128 + ((slotk ^ (row & 7)) << 4);
      half8 ah = *(const half8*)((char*)Ah + byte);
      half8 al = *(const half8*)((char*)Al + byte);
#pragma unroll
      for (int ci = 0; ci < 2; ++ci) {
        acc[rt][ci] = __builtin_amdgcn_mfma_f32_16x16x32_f16(ah, bfh[ci], acc[rt][ci], 0, 0, 0);
        acc[rt][ci] = __builtin_amdgcn_mfma_f32_16x16x32_f16(ah, bfl[ci], acc[rt][ci], 0, 0, 0);
        acc[rt][ci] = __builtin_amdgcn_mfma_f32_16x16x32_f16(al, bfh[ci], acc[rt][ci], 0, 0, 0);
      }
    }
  }
  __syncthreads();   // A/B reads done -> outb may overwrite
#pragma unroll
  for (int rt = 0; rt < 5; ++rt)
#pragma unroll
    for (int ci = 0; ci < 2; ++ci) {
      int col = (wave * 2 + ci) * 16 + l15;
#pragma unroll
      for (int q = 0; q < 4; ++q) {
        int row = rt * 16 + l4 * 4 + q;
        outb[row * 129 + col] = acc[rt][ci][q];
      }
    }
  __syncthreads();
#pragma unroll
  for (int r = 0; r < 2; ++r) {
    int it = tid + 256 * r;          // 512 items: p = it>>7, c = it&127
    int p = it >> 7, c = it & 127;
    float mx = -1e30f;
#pragma unroll
    for (int e = 0; e < 20; ++e) mx = fmaxf(mx, outb[(p * 20 + e) * 129 + c]);
    x1[((size_t)bid * 4 + p) * 128 + c] = mx + b2v[c];
  }
}

// ---------------- c1 [2,1024,4,52,7] -> Cf16 [1024][3328], reordered k-axis ----------------
// k = w*64 + (phase*4 + n)*8 + g; slot e==7 zero-padded.
__global__ void c1_to_f16_kernel(const float* __restrict__ c1, _Float16* __restrict__ Cf) {
  int L = blockIdx.x * 256 + threadIdx.x;
  if (L >= 1024 * 3328) return;
  int o = L / 3328, rem = L % 3328;
  int w = rem >> 6, idx = rem & 63;
  int s = idx >> 3, e = idx & 7;
  int phase = s >> 2, n = s & 3;
  float v = 0.0f;
  if (e < 7)
    v = c1[((((size_t)phase * 1024 + o) * 4 + n) * 52 + w) * 7 + e];
  Cf[L] = (_Float16)v;
}

// ---------------- KAN1 MFMA GEMM [32768,3328]x[3328,1024] ----------------
// BM=256 BN=128 BK=64 (1 tap/iter), 512 thr (8 waves 4x2), wave tile 64x64.
// A-fragments computed IN REGISTERS (no LDS roundtrip): lane (l15,l4) of wave
// (wr,wc) owns trig for x[wr*64+mi*16+l15][l4*20+t]; one sincos feeds BOTH the
// cos (ksub0) and sin (ksub1) fragment via dual Chebyshev chains. B stays in a
// 2x16KB double-buffered LDS (gload_lds, pre-swizzled src). x reg-prefetched.
// LDS = 32 KB -> 2 blocks/CU (4 waves/SIMD) for cross-block stall hiding.
__global__ __launch_bounds__(512, 4) void kan1_gemm_kernel(
    const float* __restrict__ x1, const _Float16* __restrict__ Cf,
    float* __restrict__ pmax, float* __restrict__ psump) {
  __shared__ __align__(16) _Float16 Bsm[2][128 * 64];  // 2 x 16 KB, swizzled
  int tid = threadIdx.x;
  int bm = blockIdx.x, bn = blockIdx.y;
  int m0 = bm << 8, n0 = bn << 7;
  int wave = tid >> 6, lane = tid & 63;
  int wr = wave >> 1, wc = wave & 1;        // 4 x 2 wave grid
  int l15 = lane & 15, l4 = lane >> 4;

  auto stageB = [&](int t, int nb) {
    int j0 = t << 6;
#pragma unroll
    for (int i = 0; i < 2; ++i) {
      int idx = i * 512 + tid;          // 0..1023 : col = idx>>3, slot = idx&7
      int col = idx >> 3, slot = idx & 7;
      int sslot = slot ^ (col & 7);
      gload16(Cf + (size_t)(n0 + col) * 3328 + j0 + sslot * 8,
              (char*)Bsm[nb] + idx * 16);
    }
  };

  const float* xbase = x1 + (size_t)(m0 + wr * 64 + l15) * 128 + l4 * 20;
  float xr[4];
#pragma unroll
  for (int mi = 0; mi < 4; ++mi) xr[mi] = xbase[mi * 2048];
  stageB(0, 0);
  f32x4 acc[4][4] = {};
  __syncthreads();                       // Bsm[0] staged + xr loaded

  for (int t = 0; t < 52; ++t) {
    int cur = t & 1, nxt = cur ^ 1;
    if (t < 51) stageB(t + 1, nxt);      // in-flight until end-of-iter barrier
    // ---- A fragments in registers: 1 sincos + dual Chebyshev per mi ----
    float bart = 1.0f - fabsf((float)(2 * t) * (1.0f / 52.0f) - 1.0f);
    half8 a0[4], a1[4];
#pragma unroll
    for (int mi = 0; mi < 4; ++mi) {
      float th = xr[mi] * bart;
      float sn, cs;
      __sincosf(th, &sn, &cs);
      float c2 = 2.0f * cs;
      float cp2 = cs, cp1 = c2 * cs - 1.0f;
      float sp2 = sn, sp1 = c2 * sn;
      a0[mi][0] = (_Float16)cp2; a0[mi][1] = (_Float16)cp1;
      a1[mi][0] = (_Float16)sp2; a1[mi][1] = (_Float16)sp1;
#pragma unroll
      for (int e = 2; e < 7; ++e) {
        float cn = c2 * cp1 - cp2; cp2 = cp1; cp1 = cn;
        float sv = c2 * sp1 - sp2; sp2 = sp1; sp1 = sv;
        a0[mi][e] = (_Float16)cn; a1[mi][e] = (_Float16)sv;
      }
      a0[mi][7] = (_Float16)0.0f; a1[mi][7] = (_Float16)0.0f;
    }
    if (t < 51) {                        // x prefetch for next tap (reg, hidden)
#pragma unroll
      for (int mi = 0; mi < 4; ++mi) xr[mi] = xbase[mi * 2048 + t + 1];
    }
    // ---- ksub 0 (cos half, slots l4) ----
    {
      half8 bf[4];
#pragma unroll
      for (int ni = 0; ni < 4; ++ni) {
        int col = wc * 64 + ni * 16 + l15;
        bf[ni] = *(const half8*)((char*)Bsm[cur] + col * 128 + ((l4 ^ (col & 7)) << 4));
      }
#pragma unroll
      for (int mi = 0; mi < 4; ++mi)
#pragma unroll
        for (int ni = 0; ni < 4; ++ni)
          acc[mi][ni] = __builtin_amdgcn_mfma_f32_16x16x32_f16(a0[mi], bf[ni], acc[mi][ni], 0, 0, 0);
    }
    // ---- ksub 1 (sin half, slots 4+l4) ----
    {
      half8 bf[4];
#pragma unroll
      for (int ni = 0; ni < 4; ++ni) {
        int col = wc * 64 + ni * 16 + l15;
        bf[ni] = *(const half8*)((char*)Bsm[cur] + col * 128 + (((4 + l4) ^ (col & 7)) << 4));
      }
#pragma unroll
      for (int mi = 0; mi < 4; ++mi)
#pragma unroll
        for (int ni = 0; ni < 4; ++ni)
          acc[mi][ni] = __builtin_amdgcn_mfma_f32_16x16x32_f16(a1[mi], bf[ni], acc[mi][ni], 0, 0, 0);
    }
    __syncthreads();
  }

  // ---- fused pooling epilogue: max/sum over the block's 256 rows ----
  float* pooled = (float*)Bsm;           // [4 wr][max|sum][128], 4 KB
#pragma unroll
  for (int ni = 0; ni < 4; ++ni) {
    float mx = -1e30f, sm = 0.f;
#pragma unroll
    for (int mi = 0; mi < 4; ++mi)
#pragma unroll
      for (int q = 0; q < 4; ++q) {
        float v = acc[mi][ni][q];
        mx = fmaxf(mx, v); sm += v;
      }
    mx = fmaxf(mx, __shfl_xor(mx, 16)); sm += __shfl_xor(sm, 16);
    mx = fmaxf(mx, __shfl_xor(mx, 32)); sm += __shfl_xor(sm, 32);
    if (l4 == 0) {
      int col = wc * 64 + ni * 16 + l15;
      pooled[(wr * 2 + 0) * 128 + col] = mx;
      pooled[(wr * 2 + 1) * 128 + col] = sm;
    }
  }
  __syncthreads();
  if (tid < 128) {
    float mx = pooled[tid], sm = pooled[128 + tid];
#pragma unroll
    for (int w = 1; w < 4; ++w) {
      mx = fmaxf(mx, pooled[(w * 2 + 0) * 128 + tid]);
      sm += pooled[(w * 2 + 1) * 128 + tid];
    }
    pmax[(size_t)bm * 1024 + n0 + tid] = mx;
    psump[(size_t)bm * 1024 + n0 + tid] = sm;
  }
}

// ---------------- final pool: 4 m-block partials -> gmax/gmean (+bi1) ----------------
__global__ void pool_reduce_kernel(const float* __restrict__ pmax, const float* __restrict__ psump,
                                   const float* __restrict__ bi1,
                                   float* __restrict__ gmax, float* __restrict__ gmean) {
  int gid = blockIdx.x * 256 + threadIdx.x;   // 32768 = 32 graphs x 1024 cols
  int b = gid >> 10, col = gid & 1023;
  float mx = -1e30f, sm = 0.f;
  for (int t = 0; t < 4; ++t) {
    mx = fmaxf(mx, pmax[(size_t)(b * 4 + t) * 1024 + col]);
    sm += psump[(size_t)(b * 4 + t) * 1024 + col];
  }
  float bias = bi1[col];
  gmax[gid] = mx + bias;
  gmean[gid] = sm * (1.0f / 1024.0f) + bias;
}

// ---------------- STFT-KAN2 partials: xcat [32,2048] -> part [32,16,7] ----------------
__global__ __launch_bounds__(256) void kan2_kernel(
    const float* __restrict__ gmax, const float* __restrict__ gmean,
    const float* __restrict__ c2, float* __restrict__ part) {
  __shared__ float xc[2048];
  __shared__ float hw[197];
  __shared__ float racc[7][256];
  int b = blockIdx.x, s = blockIdx.y, tid = threadIdx.x;
  for (int f = tid; f < 1024; f += 256) {
    xc[f] = gmax[b * 1024 + f];
    xc[1024 + f] = gmean[b * 1024 + f];
  }
  for (int f = tid; f < 197; f += 256)
    hw[f] = 0.5f * (1.0f - cosf(6.283185307179586f * (float)f / 197.0f));
  float acc[7] = {};
  __syncthreads();
  int qlo = (52205 * s) / 16, qhi = (52205 * (s + 1)) / 16;
  for (int q = qlo + tid; q < qhi; q += 256) {
    int n = q / 197;
    int w = q - n * 197;
    float xw = xc[n * 7 + w] * hw[w];
    float s1, c1v;
    __sincosf(xw, &s1, &c1v);
    float ckv[6], skv[6];
    {
      float ck = c1v, sk = s1;
#pragma unroll
      for (int g = 0; g < 6; ++g) {
        ckv[g] = ck; skv[g] = sk;
        float cn = ck * c1v - sk * s1;
        sk = sk * c1v + ck * s1;
        ck = cn;
      }
    }
    int base = q * 6;
#pragma unroll
    for (int o = 0; o < 7; ++o) {
      const float* pc = c2 + (size_t)o * 313230 + base;
      const float* ps = c2 + (size_t)(o + 7) * 313230 + base;
      float sc = 0.f, ss = 0.f;
#pragma unroll
      for (int g = 0; g < 6; ++g) { sc += ckv[g] * pc[g]; ss += skv[g] * ps[g]; }
      acc[o] += sc + ss;
    }
  }
#pragma unroll
  for (int o = 0; o < 7; ++o) racc[o][tid] = acc[o];
  __syncthreads();
  for (int st = 128; st >= 1; st >>= 1) {
    if (tid < st)
#pragma unroll
      for (int o = 0; o < 7; ++o) racc[o][tid] += racc[o][tid + st];
    __syncthreads();
  }
  if (tid < 7) part[(b * 16 + s) * 7 + tid] = racc[tid][0];
}

__global__ void kan2_reduce_kernel(const float* __restrict__ part, const float* __restrict__ bi2,
                                   float* __restrict__ out) {
  int i = threadIdx.x;   // 224 threads: (b, o)
  if (i >= 224) return;
  int b = i / 7, o = i % 7;
  float s = 0.f;
  for (int t = 0; t < 16; ++t) s += part[(b * 16 + t) * 7 + o];
  out[b * 7 + o] = s + bi2[o];
}

// ---------------------------------------------------------------------------
extern "C" void kernel_launch(void* const* d_in, const int* in_sizes, int n_in,
                              void* d_out, int out_size, void* d_ws, size_t ws_size,
                              hipStream_t stream) {
  const float* pos    = (const float*)d_in[0];
  const float* W1     = (const float*)d_in[2];
  const float* b1     = (const float*)d_in[3];
  const float* gamma1 = (const float*)d_in[4];
  const float* beta1  = (const float*)d_in[5];
  const float* W2     = (const float*)d_in[6];
  const float* b2     = (const float*)d_in[7];
  const float* c1     = (const float*)d_in[8];
  const float* bi1    = (const float*)d_in[9];
  const float* c2     = (const float*)d_in[10];
  const float* bi2    = (const float*)d_in[11];
  float* out = (float*)d_out;
  char* ws = (char*)d_ws;

  int*      nbr   = (int*)     (ws + 0);          // 2,621,440
  float*    x1    = (float*)   (ws + 2621440);    // 16,777,216
  _Float16* Cf    = (_Float16*)(ws + 19398656);   // 1024*3328*2 = 6,815,744
  float*    psum  = (float*)   (ws + 26214400);   // 131,072
  float*    psq   = (float*)   (ws + 26345472);   // 131,072
  float*    bns   = (float*)   (ws + 26476544);   // 256
  float*    bnh   = (float*)   (ws + 26476800);   // 256
  float*    pmax  = (float*)   (ws + 26477056);   // 128*1024*4 = 524,288
  float*    psump = (float*)   (ws + 27001344);   // 524,288
  float*    gmax  = (float*)   (ws + 27525632);   // 131,072
  float*    gmean = (float*)   (ws + 27656704);   // 131,072
  float*    part  = (float*)   (ws + 27787776);   // 14,336
  if (ws_size < 27802112) return;

  knn_kernel<<<8192, 256, 0, stream>>>(pos, nbr);
  c1_to_f16_kernel<<<13312, 256, 0, stream>>>(c1, Cf);
  edge_stats_kernel<<<512, 256, 0, stream>>>(pos, nbr, W1, b1, psum, psq);
  bn_finalize_kernel<<<1, 64, 0, stream>>>(psum, psq, gamma1, beta1, bns, bnh);
  edge_mlp_kernel<<<8192, 256, 0, stream>>>(pos, nbr, W1, b1, bns, bnh, W2, b2, x1);
  kan1_gemm_kernel<<<dim3(128, 8), 512, 0, stream>>>(x1, Cf, pmax, psump);
  pool_reduce_kernel<<<128, 256, 0, stream>>>(pmax, psump, bi1, gmax, gmean);
  kan2_kernel<<<dim3(32, 16), 256, 0, stream>>>(gmax, gmean, c2, part);
  kan2_reduce_kernel<<<1, 256, 0, stream>>>(part, bi2, out);
}

// Round 9
// 593.137 us; speedup vs baseline: 1.0198x; 1.0198x over previous
//
#include <hip/hip_runtime.h>
#include <cstdint>

typedef _Float16 half8 __attribute__((ext_vector_type(8)));
typedef __fp16 fp16x2 __attribute__((ext_vector_type(2)));
typedef float f32x2 __attribute__((ext_vector_type(2)));
typedef float f32x4 __attribute__((ext_vector_type(4)));

__device__ __forceinline__ void gload16(const void* g, void* l) {
  __builtin_amdgcn_global_load_lds(
      (const __attribute__((address_space(1))) void*)g,
      (__attribute__((address_space(3))) void*)l, 16, 0, 0);
}

// ---------------- kNN: one WAVE per query point, barrier-free selection ----------------
__global__ __launch_bounds__(256) void knn_kernel(const float* __restrict__ pos,
                                                  int* __restrict__ nbr) {
  __shared__ float px[1024], py[1024], pz[1024], sq[1024];
  int tid = threadIdx.x;
  int b = blockIdx.x >> 8;                 // graph id (256 blocks per graph)
  const float* pg = pos + (size_t)b * 3072;
  for (int m = 0; m < 4; ++m) {
    int j = m * 256 + tid;
    float x = pg[3 * j], y = pg[3 * j + 1], z = pg[3 * j + 2];
    px[j] = x; py[j] = y; pz[j] = z; sq[j] = x * x + y * y + z * z;
  }
  __syncthreads();
  int wave = tid >> 6, lane = tid & 63;
  int n = (blockIdx.x & 255) * 4 + wave;   // local query index in graph
  float xi = px[n], yi = py[n], zi = pz[n], si = sq[n];
  float d[16];
#pragma unroll
  for (int i = 0; i < 16; ++i) {
    int j = i * 64 + lane;
    float dd = si + sq[j] - 2.0f * (xi * px[j] + yi * py[j] + zi * pz[j]);
    d[i] = (j == n) ? 1e30f : dd;          // exclude self
  }
  int outbase = (b * 1024 + n) * 20;
  for (int kk = 0; kk < 20; ++kk) {
    float lmin = d[0]; int lpos = 0;
#pragma unroll
    for (int i = 1; i < 16; ++i)
      if (d[i] < lmin) { lmin = d[i]; lpos = i; }
    float bv = lmin; int bi = lpos * 64 + lane;
#pragma unroll
    for (int off = 1; off < 64; off <<= 1) {
      float ov = __shfl_xor(bv, off);
      int   oi = __shfl_xor(bi, off);
      if (ov < bv || (ov == bv && oi < bi)) { bv = ov; bi = oi; }
    }
    if (lane == 0) nbr[outbase + kk] = b * 1024 + bi;
    if ((bi & 63) == lane) {
      int rp = bi >> 6;
#pragma unroll
      for (int i = 0; i < 16; ++i)
        if (i == rp) d[i] = 1e30f;
    }
  }
}

// ---------------- edge MLP layer1 stats (sum, sumsq per channel) ----------------
__global__ __launch_bounds__(256) void edge_stats_kernel(
    const float* __restrict__ pos, const int* __restrict__ nbr,
    const float* __restrict__ W1, const float* __restrict__ b1v,
    float* __restrict__ psum, float* __restrict__ psq) {
  __shared__ float els[256][6];
  __shared__ float w1s[384];
  __shared__ float b1s[64];
  __shared__ float red[8][64];
  int tid = threadIdx.x, bid = blockIdx.x;
  for (int f = tid; f < 384; f += 256) w1s[f] = W1[f];
  if (tid < 64) b1s[tid] = b1v[tid];
  int c = tid & 63, grp = tid >> 6;
  float s = 0.f, s2 = 0.f;
  for (int ch = 0; ch < 5; ++ch) {
    int E = bid * 1280 + ch * 256 + tid;
    int p = E / 20;
    int j = nbr[E];
    float pix = pos[3 * p], piy = pos[3 * p + 1], piz = pos[3 * p + 2];
    float e3 = pos[3 * j] - pix, e4 = pos[3 * j + 1] - piy, e5 = pos[3 * j + 2] - piz;
    __syncthreads();
    els[tid][0] = pix; els[tid][1] = piy; els[tid][2] = piz;
    els[tid][3] = e3;  els[tid][4] = e4;  els[tid][5] = e5;
    __syncthreads();
    for (int m = 0; m < 64; ++m) {
      int e = grp * 64 + m;
      float h = b1s[c];
#pragma unroll
      for (int d = 0; d < 6; ++d) h += els[e][d] * w1s[d * 64 + c];
      s += h; s2 += h * h;
    }
  }
  red[grp][c] = s;
  __syncthreads();
  red[4 + grp][c] = s2;
  __syncthreads();
  if (tid < 64) {
    float S = red[0][tid] + red[1][tid] + red[2][tid] + red[3][tid];
    float Q = red[4][tid] + red[5][tid] + red[6][tid] + red[7][tid];
    psum[bid * 64 + tid] = S;
    psq[bid * 64 + tid] = Q;
  }
}

__global__ void bn_finalize_kernel(const float* __restrict__ psum, const float* __restrict__ psq,
                                   const float* __restrict__ gamma, const float* __restrict__ beta,
                                   float* __restrict__ bns, float* __restrict__ bnh) {
  int c = threadIdx.x;   // 64 threads
  float s = 0.f, q = 0.f;
  for (int b = 0; b < 512; ++b) { s += psum[b * 64 + c]; q += psq[b * 64 + c]; }
  const float inv = 1.0f / 655360.0f;
  float mu = s * inv;
  float var = q * inv - mu * mu;
  float sc = gamma[c] * rsqrtf(var + 1e-5f);
  bns[c] = sc;
  bnh[c] = beta[c] - mu * sc;
}

// ---------------- edge MLP via split-f16 MFMA (fp32-accurate) ----------------
__global__ __launch_bounds__(256) void edge_mlp_kernel(
    const float* __restrict__ pos, const int* __restrict__ nbr,
    const float* __restrict__ W1, const float* __restrict__ b1v,
    const float* __restrict__ bns, const float* __restrict__ bnh,
    const float* __restrict__ W2, const float* __restrict__ b2v,
    float* __restrict__ x1) {
  __shared__ __align__(16) char elds[53248];
  _Float16* Ah = (_Float16*)(elds);            // [80][64] swizzled, 10240 B
  _Float16* Al = (_Float16*)(elds + 10240);    // 10240 B
  _Float16* Bh = (_Float16*)(elds + 20480);    // [128 cols][64] swizzled, 16384 B
  _Float16* Bl = (_Float16*)(elds + 36864);    // 16384 B
  float* outb = (float*)elds;                  // [80][129] fp32, reused after MFMA
  __shared__ float w1s[384];
  __shared__ float b1s[64], scs[64], shs[64];
  int tid = threadIdx.x, bid = blockIdx.x;
  for (int f = tid; f < 384; f += 256) w1s[f] = W1[f];
  if (tid < 64) { b1s[tid] = b1v[tid]; scs[tid] = bns[tid]; shs[tid] = bnh[tid]; }
#pragma unroll
  for (int i = 0; i < 32; ++i) {
    int flat = tid + 256 * i;        // d = flat>>7 (0..63), c = flat&127
    int dd = flat >> 7, c = flat & 127;
    float v = W2[flat];
    _Float16 hi = (_Float16)v;
    _Float16 lo = (_Float16)(v - (float)hi);
    int byte = c * 128 + ((((dd >> 3) ^ (c & 7))) << 4) + (dd & 7) * 2;
    *(_Float16*)((char*)Bh + byte) = hi;
    *(_Float16*)((char*)Bl + byte) = lo;
  }
  __syncthreads();
#pragma unroll
  for (int m = 0; m < 20; ++m) {
    int flat = tid + 256 * m;
    int row = flat >> 6;            // 0..79
    int d = flat & 63;
    int j = nbr[bid * 80 + row];
    int P = bid * 4 + (row / 20);
    float pix = pos[3 * P], piy = pos[3 * P + 1], piz = pos[3 * P + 2];
    float e3 = pos[3 * j] - pix, e4 = pos[3 * j + 1] - piy, e5 = pos[3 * j + 2] - piz;
    float h = b1s[d];
    h += pix * w1s[d] + piy * w1s[64 + d] + piz * w1s[128 + d]
       + e3 * w1s[192 + d] + e4 * w1s[256 + d] + e5 * w1s[320 + d];
    h = scs[d] * h + shs[d];
    h = fmaxf(h, 0.f);
    _Float16 hi = (_Float16)h;
    _Float16 lo = (_Float16)(h - (float)hi);
    int byte = row * 128 + ((((d >> 3) ^ (row & 7))) << 4) + (d & 7) * 2;
    *(_Float16*)((char*)Ah + byte) = hi;
    *(_Float16*)((char*)Al + byte) = lo;
  }
  __syncthreads();
  int wave = tid >> 6, lane = tid & 63;
  int l15 = lane & 15, l4 = lane >> 4;
  f32x4 acc[5][2] = {};
#pragma unroll
  for (int ks = 0; ks < 2; ++ks) {
    int slotk = ks * 4 + l4;
    half8 bfh[2], bfl[2];
#pragma unroll
    for (int ci = 0; ci < 2; ++ci) {
      int col = (wave * 2 + ci) * 16 + l15;
      int byte = col * 128 + ((slotk ^ (col & 7)) << 4);
      bfh[ci] = *(const half8*)((char*)Bh + byte);
      bfl[ci] = *(const half8*)((char*)Bl + byte);
    }
#pragma unroll
    for (int rt = 0; rt < 5; ++rt) {
      int row = rt * 16 + l15;
      int byte = row * 128 + ((slotk ^ (row & 7)) << 4);
      half8 ah = *(const half8*)((char*)Ah + byte);
      half8 al = *(const half8*)((char*)Al + byte);
#pragma unroll
      for (int ci = 0; ci < 2; ++ci) {
        acc[rt][ci] = __builtin_amdgcn_mfma_f32_16x16x32_f16(ah, bfh[ci], acc[rt][ci], 0, 0, 0);
        acc[rt][ci] = __builtin_amdgcn_mfma_f32_16x16x32_f16(ah, bfl[ci], acc[rt][ci], 0, 0, 0);
        acc[rt][ci] = __builtin_amdgcn_mfma_f32_16x16x32_f16(al, bfh[ci], acc[rt][ci], 0, 0, 0);
      }
    }
  }
  __syncthreads();   // A/B reads done -> outb may overwrite
#pragma unroll
  for (int rt = 0; rt < 5; ++rt)
#pragma unroll
    for (int ci = 0; ci < 2; ++ci) {
      int col = (wave * 2 + ci) * 16 + l15;
#pragma unroll
      for (int q = 0; q < 4; ++q) {
        int row = rt * 16 + l4 * 4 + q;
        outb[row * 129 + col] = acc[rt][ci][q];
      }
    }
  __syncthreads();
#pragma unroll
  for (int r = 0; r < 2; ++r) {
    int it = tid + 256 * r;          // 512 items: p = it>>7, c = it&127
    int p = it >> 7, c = it & 127;
    float mx = -1e30f;
#pragma unroll
    for (int e = 0; e < 20; ++e) mx = fmaxf(mx, outb[(p * 20 + e) * 129 + c]);
    x1[((size_t)bid * 4 + p) * 128 + c] = mx + b2v[c];
  }
}

// ---------------- c1 [2,1024,4,52,7] -> Cf16 [1024][3328], interleaved (cos,sin) pairs ----
// k = t*64 + (half*4 + n)*8 + e ; e -> phase = e&1, g_idx = half*4 + (e>>1).
// half==1, e>=6 -> zero pad. Pairs let A-gen emit fragments via cvt_pkrtz directly.
__global__ void c1_to_f16_kernel(const float* __restrict__ c1, _Float16* __restrict__ Cf) {
  int L = blockIdx.x * 256 + threadIdx.x;
  if (L >= 1024 * 3328) return;
  int o = L / 3328, rem = L % 3328;
  int t = rem >> 6, idx = rem & 63;
  int s = idx >> 3, e = idx & 7;
  int half = s >> 2, n = s & 3;
  float v = 0.0f;
  if (!(half == 1 && e >= 6)) {
    int phase = e & 1;
    int g0 = half * 4 + (e >> 1);   // 0..6 = k-1
    v = c1[((((size_t)phase * 1024 + o) * 4 + n) * 52 + t) * 7 + g0];
  }
  Cf[L] = (_Float16)v;
}

// ---------------- KAN1 MFMA GEMM [32768,3328]x[3328,1024] ----------------
// BM=256 BN=128 BK=64 (1 tap/iter), 512 thr (8 waves 4x2), wave tile 64x64.
// A fragments in registers via PACKED pair math: one sincos per (mi,tap), then
// f32x2 Chebyshev computing cos&sin chains together, and cvt_pkrtz emitting
// the interleaved fragment directly. ksub0 frag = pairs g1..g4, ksub1 = g5..g7+(0,0).
// B double-buffered in LDS (gload_lds, pre-swizzled src). 2 blocks/CU.
__global__ __launch_bounds__(512, 4) void kan1_gemm_kernel(
    const float* __restrict__ x1, const _Float16* __restrict__ Cf,
    float* __restrict__ pmax, float* __restrict__ psump) {
  __shared__ __align__(16) _Float16 Bsm[2][128 * 64];  // 2 x 16 KB, swizzled
  int tid = threadIdx.x;
  int bm = blockIdx.x, bn = blockIdx.y;
  int m0 = bm << 8, n0 = bn << 7;
  int wave = tid >> 6, lane = tid & 63;
  int wr = wave >> 1, wc = wave & 1;        // 4 x 2 wave grid
  int l15 = lane & 15, l4 = lane >> 4;

  auto stageB = [&](int t, int nb) {
    int j0 = t << 6;
#pragma unroll
    for (int i = 0; i < 2; ++i) {
      int idx = i * 512 + tid;          // 0..1023 : col = idx>>3, slot = idx&7
      int col = idx >> 3, slot = idx & 7;
      int sslot = slot ^ (col & 7);
      gload16(Cf + (size_t)(n0 + col) * 3328 + j0 + sslot * 8,
              (char*)Bsm[nb] + idx * 16);
    }
  };

  const float* xbase = x1 + (size_t)(m0 + wr * 64 + l15) * 128 + l4 * 20;
  float xr[4];
#pragma unroll
  for (int mi = 0; mi < 4; ++mi) xr[mi] = xbase[mi * 2048];
  stageB(0, 0);
  f32x4 acc[4][4] = {};
  __syncthreads();                       // Bsm[0] staged + xr loaded

  for (int t = 0; t < 52; ++t) {
    int cur = t & 1, nxt = cur ^ 1;
    if (t < 51) stageB(t + 1, nxt);      // in-flight until end-of-iter barrier
    // ---- A fragments in registers: 1 sincos + packed-pair Chebyshev per mi ----
    float bart = 1.0f - fabsf((float)(2 * t) * (1.0f / 52.0f) - 1.0f);
    half8 a0[4], a1[4];
#pragma unroll
    for (int mi = 0; mi < 4; ++mi) {
      float th = xr[mi] * bart;
      float sn, cs;
      __sincosf(th, &sn, &cs);
      float c2s = cs + cs;
      f32x2 c2v = {c2s, c2s};
      f32x2 p1 = {cs, sn};
      f32x2 p2 = c2v * p1 - (f32x2){1.0f, 0.0f};
      f32x2 p3 = c2v * p2 - p1;
      f32x2 p4 = c2v * p3 - p2;
      f32x2 p5 = c2v * p4 - p3;
      f32x2 p6 = c2v * p5 - p4;
      f32x2 p7 = c2v * p6 - p5;
      union { half8 v; fp16x2 q[4]; } u0, u1;
      u0.q[0] = __builtin_amdgcn_cvt_pkrtz(p1.x, p1.y);
      u0.q[1] = __builtin_amdgcn_cvt_pkrtz(p2.x, p2.y);
      u0.q[2] = __builtin_amdgcn_cvt_pkrtz(p3.x, p3.y);
      u0.q[3] = __builtin_amdgcn_cvt_pkrtz(p4.x, p4.y);
      u1.q[0] = __builtin_amdgcn_cvt_pkrtz(p5.x, p5.y);
      u1.q[1] = __builtin_amdgcn_cvt_pkrtz(p6.x, p6.y);
      u1.q[2] = __builtin_amdgcn_cvt_pkrtz(p7.x, p7.y);
      u1.q[3] = (fp16x2){(__fp16)0.0f, (__fp16)0.0f};
      a0[mi] = u0.v;
      a1[mi] = u1.v;
    }
    if (t < 51) {                        // x prefetch for next tap (reg, hidden)
#pragma unroll
      for (int mi = 0; mi < 4; ++mi) xr[mi] = xbase[mi * 2048 + t + 1];
    }
    // ---- ksub 0 (pairs g1..g4, slots l4) ----
    {
      half8 bf[4];
#pragma unroll
      for (int ni = 0; ni < 4; ++ni) {
        int col = wc * 64 + ni * 16 + l15;
        bf[ni] = *(const half8*)((char*)Bsm[cur] + col * 128 + ((l4 ^ (col & 7)) << 4));
      }
#pragma unroll
      for (int mi = 0; mi < 4; ++mi)
#pragma unroll
        for (int ni = 0; ni < 4; ++ni)
          acc[mi][ni] = __builtin_amdgcn_mfma_f32_16x16x32_f16(a0[mi], bf[ni], acc[mi][ni], 0, 0, 0);
    }
    // ---- ksub 1 (pairs g5..g7, slots 4+l4) ----
    {
      half8 bf[4];
#pragma unroll
      for (int ni = 0; ni < 4; ++ni) {
        int col = wc * 64 + ni * 16 + l15;
        bf[ni] = *(const half8*)((char*)Bsm[cur] + col * 128 + (((4 + l4) ^ (col & 7)) << 4));
      }
#pragma unroll
      for (int mi = 0; mi < 4; ++mi)
#pragma unroll
        for (int ni = 0; ni < 4; ++ni)
          acc[mi][ni] = __builtin_amdgcn_mfma_f32_16x16x32_f16(a1[mi], bf[ni], acc[mi][ni], 0, 0, 0);
    }
    __syncthreads();
  }

  // ---- fused pooling epilogue: max/sum over the block's 256 rows ----
  float* pooled = (float*)Bsm;           // [4 wr][max|sum][128], 4 KB
#pragma unroll
  for (int ni = 0; ni < 4; ++ni) {
    float mx = -1e30f, sm = 0.f;
#pragma unroll
    for (int mi = 0; mi < 4; ++mi)
#pragma unroll
      for (int q = 0; q < 4; ++q) {
        float v = acc[mi][ni][q];
        mx = fmaxf(mx, v); sm += v;
      }
    mx = fmaxf(mx, __shfl_xor(mx, 16)); sm += __shfl_xor(sm, 16);
    mx = fmaxf(mx, __shfl_xor(mx, 32)); sm += __shfl_xor(sm, 32);
    if (l4 == 0) {
      int col = wc * 64 + ni * 16 + l15;
      pooled[(wr * 2 + 0) * 128 + col] = mx;
      pooled[(wr * 2 + 1) * 128 + col] = sm;
    }
  }
  __syncthreads();
  if (tid < 128) {
    float mx = pooled[tid], sm = pooled[128 + tid];
#pragma unroll
    for (int w = 1; w < 4; ++w) {
      mx = fmaxf(mx, pooled[(w * 2 + 0) * 128 + tid]);
      sm += pooled[(w * 2 + 1) * 128 + tid];
    }
    pmax[(size_t)bm * 1024 + n0 + tid] = mx;
    psump[(size_t)bm * 1024 + n0 + tid] = sm;
  }
}

// ---------------- final pool: 4 m-block partials -> gmax/gmean (+bi1) ----------------
__global__ void pool_reduce_kernel(const float* __restrict__ pmax, const float* __restrict__ psump,
                                   const float* __restrict__ bi1,
                                   float* __restrict__ gmax, float* __restrict__ gmean) {
  int gid = blockIdx.x * 256 + threadIdx.x;   // 32768 = 32 graphs x 1024 cols
  int b = gid >> 10, col = gid & 1023;
  float mx = -1e30f, sm = 0.f;
  for (int t = 0; t < 4; ++t) {
    mx = fmaxf(mx, pmax[(size_t)(b * 4 + t) * 1024 + col]);
    sm += psump[(size_t)(b * 4 + t) * 1024 + col];
  }
  float bias = bi1[col];
  gmax[gid] = mx + bias;
  gmean[gid] = sm * (1.0f / 1024.0f) + bias;
}

// ---------------- STFT-KAN2 partials: xcat [32,2048] -> part [32,16,7] ----------------
__global__ __launch_bounds__(256) void kan2_kernel(
    const float* __restrict__ gmax, const float* __restrict__ gmean,
    const float* __restrict__ c2, float* __restrict__ part) {
  __shared__ float xc[2048];
  __shared__ float hw[197];
  __shared__ float racc[7][256];
  int b = blockIdx.x, s = blockIdx.y, tid = threadIdx.x;
  for (int f = tid; f < 1024; f += 256) {
    xc[f] = gmax[b * 1024 + f];
    xc[1024 + f] = gmean[b * 1024 + f];
  }
  for (int f = tid; f < 197; f += 256)
    hw[f] = 0.5f * (1.0f - cosf(6.283185307179586f * (float)f / 197.0f));
  float acc[7] = {};
  __syncthreads();
  int qlo = (52205 * s) / 16, qhi = (52205 * (s + 1)) / 16;
  for (int q = qlo + tid; q < qhi; q += 256) {
    int n = q / 197;
    int w = q - n * 197;
    float xw = xc[n * 7 + w] * hw[w];
    float s1, c1v;
    __sincosf(xw, &s1, &c1v);
    float ckv[6], skv[6];
    {
      float ck = c1v, sk = s1;
#pragma unroll
      for (int g = 0; g < 6; ++g) {
        ckv[g] = ck; skv[g] = sk;
        float cn = ck * c1v - sk * s1;
        sk = sk * c1v + ck * s1;
        ck = cn;
      }
    }
    int base = q * 6;
#pragma unroll
    for (int o = 0; o < 7; ++o) {
      const float* pc = c2 + (size_t)o * 313230 + base;
      const float* ps = c2 + (size_t)(o + 7) * 313230 + base;
      float sc = 0.f, ss = 0.f;
#pragma unroll
      for (int g = 0; g < 6; ++g) { sc += ckv[g] * pc[g]; ss += skv[g] * ps[g]; }
      acc[o] += sc + ss;
    }
  }
#pragma unroll
  for (int o = 0; o < 7; ++o) racc[o][tid] = acc[o];
  __syncthreads();
  for (int st = 128; st >= 1; st >>= 1) {
    if (tid < st)
#pragma unroll
      for (int o = 0; o < 7; ++o) racc[o][tid] += racc[o][tid + st];
    __syncthreads();
  }
  if (tid < 7) part[(b * 16 + s) * 7 + tid] = racc[tid][0];
}

__global__ void kan2_reduce_kernel(const float* __restrict__ part, const float* __restrict__ bi2,
                                   float* __restrict__ out) {
  int i = threadIdx.x;   // 224 threads: (b, o)
  if (i >= 224) return;
  int b = i / 7, o = i % 7;
  float s = 0.f;
  for (int t = 0; t < 16; ++t) s += part[(b * 16 + t) * 7 + o];
  out[b * 7 + o] = s + bi2[o];
}

// ---------------------------------------------------------------------------
extern "C" void kernel_launch(void* const* d_in, const int* in_sizes, int n_in,
                              void* d_out, int out_size, void* d_ws, size_t ws_size,
                              hipStream_t stream) {
  const float* pos    = (const float*)d_in[0];
  const float* W1     = (const float*)d_in[2];
  const float* b1     = (const float*)d_in[3];
  const float* gamma1 = (const float*)d_in[4];
  const float* beta1  = (const float*)d_in[5];
  const float* W2     = (const float*)d_in[6];
  const float* b2     = (const float*)d_in[7];
  const float* c1     = (const float*)d_in[8];
  const float* bi1    = (const float*)d_in[9];
  const float* c2     = (const float*)d_in[10];
  const float* bi2    = (const float*)d_in[11];
  float* out = (float*)d_out;
  char* ws = (char*)d_ws;

  int*      nbr   = (int*)     (ws + 0);          // 2,621,440
  float*    x1    = (float*)   (ws + 2621440);    // 16,777,216
  _Float16* Cf    = (_Float16*)(ws + 19398656);   // 1024*3328*2 = 6,815,744
  float*    psum  = (float*)   (ws + 26214400);   // 131,072
  float*    psq   = (float*)   (ws + 26345472);   // 131,072
  float*    bns   = (float*)   (ws + 26476544);   // 256
  float*    bnh   = (float*)   (ws + 26476800);   // 256
  float*    pmax  = (float*)   (ws + 26477056);   // 128*1024*4 = 524,288
  float*    psump = (float*)   (ws + 27001344);   // 524,288
  float*    gmax  = (float*)   (ws + 27525632);   // 131,072
  float*    gmean = (float*)   (ws + 27656704);   // 131,072
  float*    part  = (float*)   (ws + 27787776);   // 14,336
  if (ws_size < 27802112) return;

  knn_kernel<<<8192, 256, 0, stream>>>(pos, nbr);
  c1_to_f16_kernel<<<13312, 256, 0, stream>>>(c1, Cf);
  edge_stats_kernel<<<512, 256, 0, stream>>>(pos, nbr, W1, b1, psum, psq);
  bn_finalize_kernel<<<1, 64, 0, stream>>>(psum, psq, gamma1, beta1, bns, bnh);
  edge_mlp_kernel<<<8192, 256, 0, stream>>>(pos, nbr, W1, b1, bns, bnh, W2, b2, x1);
  kan1_gemm_kernel<<<dim3(128, 8), 512, 0, stream>>>(x1, Cf, pmax, psump);
  pool_reduce_kernel<<<128, 256, 0, stream>>>(pmax, psump, bi1, gmax, gmean);
  kan2_kernel<<<dim3(32, 16), 256, 0, stream>>>(gmax, gmean, c2, part);
  kan2_reduce_kernel<<<1, 256, 0, stream>>>(part, bi2, out);
}